// Round 11
// baseline (69.175 us; speedup 1.0000x reference)
//
#include <hip/hip_runtime.h>
#include <math.h>

#define NR   2048
#define XD   512
#define HID  300
#define BS   256
#define NPAD 320
#define KTOT 1024
#define GSTR 304          // row stride for GPB/P0a/P0b (float4-aligned)
#define KP   320          // padded k (80 k4-slots; slots 75..79 exact zeros)
#define NPOS 32           // posfin blocks

typedef __attribute__((ext_vector_type(8))) short bf16x8;
typedef __attribute__((ext_vector_type(4))) float f32x4;

__device__ __forceinline__ float softplus_f(float x) {
    return fmaxf(x, 0.f) + log1pf(__expf(-fabsf(x)));
}
__device__ __forceinline__ unsigned short f2bf(float f) {
    unsigned int u = __float_as_uint(f);
    u += 0x7FFFu + ((u >> 16) & 1u);   // RNE
    return (unsigned short)(u >> 16);
}

// grid.x = 2048 (Aneg rows) + 2048 (Apos rows) + 320 (Wt tiles)
__global__ __launch_bounds__(256) void convert(
    const float* __restrict__ pl, const float* __restrict__ pg,
    const float* __restrict__ nl, const float* __restrict__ ng,
    const float* __restrict__ W1,
    unsigned short* __restrict__ Aneg, unsigned short* __restrict__ Apos,
    unsigned short* __restrict__ Wt, unsigned int* __restrict__ counter)
{
    const int b = blockIdx.x, tid = threadIdx.x;
    if (b == 0 && tid == 0) *counter = 0u;   // reset ticket each call
    if (b < 4096) {
        const int m = (b < 2048) ? b : b - 2048;
        const float* lo = (b < 2048) ? nl : pl;
        const float* hi = (b < 2048) ? ng : pg;
        unsigned short* dst = (b < 2048) ? Aneg : Apos;
        const int kq = tid * 4;
        const float4 v = (kq < XD) ? *(const float4*)(lo + m * XD + kq)
                                   : *(const float4*)(hi + m * XD + kq - XD);
        ushort4 o;
        o.x = f2bf(v.x); o.y = f2bf(v.y); o.z = f2bf(v.z); o.w = f2bf(v.w);
        *(ushort4*)(dst + m * KTOT + kq) = o;
    } else {
        // W1 [1024][300] -> Wt [320][1024] bf16, zero-padded rows 300..319
        __shared__ unsigned short ts[16][72];
        const int t = b - 4096;
        const int nt = t % 20, kt = t / 20;   // 20 n-tiles x 16 k-tiles
        const int n = nt * 16 + (tid & 15);
        const int kl = tid >> 4;
        #pragma unroll
        for (int j = 0; j < 4; ++j) {
            const int k = kt * 64 + kl * 4 + j;
            ts[tid & 15][kl * 4 + j] = f2bf((n < HID) ? W1[k * HID + n] : 0.f);
        }
        __syncthreads();
        const int nw = tid >> 4, kw = (tid & 15) * 4;
        ushort4 o;
        o.x = ts[nw][kw]; o.y = ts[nw][kw + 1]; o.z = ts[nw][kw + 2]; o.w = ts[nw][kw + 3];
        *(ushort4*)(Wt + (nt * 16 + nw) * KTOT + kt * 64 + kw) = o;
    }
}

// One wave per block, 32x32 tile of 16x16x32 MFMAs, all jobs K=512.
// job 0 writes ALL n<320 -> LP4 k4-slots 75..79 are exact zeros.
__global__ __launch_bounds__(64) void mfma_gemm(
    const unsigned short* __restrict__ Aneg, const unsigned short* __restrict__ Apos,
    const unsigned short* __restrict__ Wt, const float* __restrict__ b1,
    float* __restrict__ LP4, float* __restrict__ GPB,
    float* __restrict__ P0a, float* __restrict__ P0b)
{
    const int job = blockIdx.z;
    const int m0 = blockIdx.x * 32, n0 = blockIdx.y * 32;
    const int lane = threadIdx.x;
    const int r = lane & 15, g = lane >> 4;

    const unsigned short* A = (job >= 2) ? Apos : Aneg;
    const int kbeg = (job & 1) ? XD : 0;

    const unsigned short* a0p = A  + (m0 + r) * KTOT + kbeg + 8 * g;
    const unsigned short* a1p = a0p + 16 * KTOT;
    const unsigned short* b0p = Wt + (n0 + r) * KTOT + kbeg + 8 * g;
    const unsigned short* b1p = b0p + 16 * KTOT;

    f32x4 acc00 = {0,0,0,0}, acc01 = {0,0,0,0}, acc10 = {0,0,0,0}, acc11 = {0,0,0,0};

    #pragma unroll
    for (int k = 0; k < XD; k += 32) {
        const bf16x8 a0 = *(const bf16x8*)(a0p + k);
        const bf16x8 a1 = *(const bf16x8*)(a1p + k);
        const bf16x8 w0 = *(const bf16x8*)(b0p + k);
        const bf16x8 w1 = *(const bf16x8*)(b1p + k);
        acc00 = __builtin_amdgcn_mfma_f32_16x16x32_bf16(a0, w0, acc00, 0, 0, 0);
        acc01 = __builtin_amdgcn_mfma_f32_16x16x32_bf16(a0, w1, acc01, 0, 0, 0);
        acc10 = __builtin_amdgcn_mfma_f32_16x16x32_bf16(a1, w0, acc10, 0, 0, 0);
        acc11 = __builtin_amdgcn_mfma_f32_16x16x32_bf16(a1, w1, acc11, 0, 0, 0);
    }

    f32x4 accs[2][2] = {{acc00, acc01}, {acc10, acc11}};
    #pragma unroll
    for (int mi = 0; mi < 2; ++mi) {
        #pragma unroll
        for (int ni = 0; ni < 2; ++ni) {
            const int n = n0 + ni * 16 + r;
            const int mb = m0 + mi * 16 + 4 * g;
            const f32x4 v = accs[mi][ni];
            if (job == 0) {
                float* base = LP4 + ((size_t)(n >> 2) * NR + mb) * 4 + (n & 3);
                base[0] = v[0]; base[4] = v[1]; base[8] = v[2]; base[12] = v[3];
            } else if (n < HID) {
                const float bias = (job == 1) ? b1[n] : 0.f;
                float* out = (job == 1) ? GPB : ((job == 2) ? P0a : P0b);
                #pragma unroll
                for (int j = 0; j < 4; ++j)
                    out[(size_t)(mb + j) * GSTR + n] = v[j] + bias;
            }
        }
    }
}

// 512 blocks x 512 threads: block = (chunk = bid>>6, 4 g-rows = (bid&63)*4).
// Waves: kh = tid>>6 (8 k-eighths of exactly 10 k4-slots), lane lh = tid&63,
// L=4 l-streams per thread. 2 blocks/CU -> 16 waves/CU (4/SIMD).
// w*relu(t) = w't + w'|t| (w'=w/2); slots 75..79 contribute exact zeros.
__global__ __launch_bounds__(512, 4) void neg_kernel(
    const float* __restrict__ LP4, const float* __restrict__ GPB,
    const float* __restrict__ W2, const float* __restrict__ b2,
    float* __restrict__ negE)
{
    __shared__ __align__(16) float w2s[KP];
    __shared__ __align__(16) float gbs[4][KP];
    __shared__ __align__(16) float pacc[8][BS][4];   // 32 KB
    __shared__ float sC[4];
    __shared__ float red[4][4];
    const int tid = threadIdx.x, bid = blockIdx.x;
    const int kh = tid >> 6, lh = tid & 63;
    const float b2v = b2[0];

    const int chunk = bid >> 6, g0 = (bid & 63) * 4;
    const float* gp = GPB + (size_t)(chunk * BS + g0) * GSTR;
    for (int idx = tid; idx < KP; idx += 512) {
        const bool v = idx < HID;
        w2s[idx]    = v ? 0.5f * W2[idx] : 0.f;
        gbs[0][idx] = v ? gp[idx] : 0.f;
        gbs[1][idx] = v ? gp[GSTR + idx] : 0.f;
        gbs[2][idx] = v ? gp[2 * GSTR + idx] : 0.f;
        gbs[3][idx] = v ? gp[3 * GSTR + idx] : 0.f;
    }
    __syncthreads();

    // sC[g] = sum_k w'_k gp[g][k]; waves 0..3 handle g = kh (padded zeros)
    if (kh < 4) {
        float c = 0.f;
        #pragma unroll
        for (int h = 0; h < 2; ++h) {
            const int k4 = lh + 64 * h;
            if (k4 < 80) {
                const float4 g4 = *(const float4*)&gbs[kh][k4 * 4];
                const float4 w4 = *(const float4*)&w2s[k4 * 4];
                c += g4.x * w4.x + g4.y * w4.y + g4.z * w4.z + g4.w * w4.w;
            }
        }
        #pragma unroll
        for (int o = 32; o > 0; o >>= 1) c += __shfl_xor(c, o);
        if (lh == 0) sC[kh] = c;
    }

    // main loop: 10 k4-slots per wave, compile-time trip count
    const int k4beg = 10 * kh;
    const float4* lpb = (const float4*)LP4 + (chunk * BS + lh);

    float acc[4][4];      // [gt][j]
    float q[4] = {0.f, 0.f, 0.f, 0.f};
    #pragma unroll
    for (int gt = 0; gt < 4; ++gt)
        #pragma unroll
        for (int j = 0; j < 4; ++j) acc[gt][j] = 0.f;

    #pragma unroll
    for (int i = 0; i < 10; ++i) {
        const int k4 = k4beg + i;
        float4 a[4];
        #pragma unroll
        for (int j = 0; j < 4; ++j)
            a[j] = lpb[(size_t)k4 * NR + 64 * j];
        const float4 w4 = *(const float4*)&w2s[k4 * 4];
        #pragma unroll
        for (int j = 0; j < 4; ++j) {
            q[j] = fmaf(w4.x, a[j].x, q[j]);
            q[j] = fmaf(w4.y, a[j].y, q[j]);
            q[j] = fmaf(w4.z, a[j].z, q[j]);
            q[j] = fmaf(w4.w, a[j].w, q[j]);
        }
        #pragma unroll
        for (int gt = 0; gt < 4; ++gt) {
            const float4 g4 = *(const float4*)&gbs[gt][k4 * 4];
            #pragma unroll
            for (int j = 0; j < 4; ++j) {
                acc[gt][j] = fmaf(fabsf(g4.x + a[j].x), w4.x, acc[gt][j]);
                acc[gt][j] = fmaf(fabsf(g4.y + a[j].y), w4.y, acc[gt][j]);
                acc[gt][j] = fmaf(fabsf(g4.z + a[j].z), w4.z, acc[gt][j]);
                acc[gt][j] = fmaf(fabsf(g4.w + a[j].w), w4.w, acc[gt][j]);
            }
        }
    }

    #pragma unroll
    for (int j = 0; j < 4; ++j)
        *(float4*)&pacc[kh][lh + 64 * j][0] =
            make_float4(acc[0][j] + q[j], acc[1][j] + q[j],
                        acc[2][j] + q[j], acc[3][j] + q[j]);
    __syncthreads();

    // combine: thread tid<256 = l; s[gt] = sC[gt] + sum_kh pacc[kh][l][gt]
    if (tid < 256) {
        float s0 = sC[0], s1 = sC[1], s2 = sC[2], s3 = sC[3];
        #pragma unroll
        for (int k = 0; k < 8; ++k) {
            const float4 p = *(const float4*)&pacc[k][tid][0];
            s0 += p.x; s1 += p.y; s2 += p.z; s3 += p.w;
        }
        float e[4];
        e[0] = __expf(softplus_f(s0 + b2v));
        e[1] = __expf(softplus_f(s1 + b2v));
        e[2] = __expf(softplus_f(s2 + b2v));
        e[3] = __expf(softplus_f(s3 + b2v));
        const int wid = tid >> 6;
        #pragma unroll
        for (int gt = 0; gt < 4; ++gt) {
            float v = e[gt];
            #pragma unroll
            for (int o = 32; o > 0; o >>= 1) v += __shfl_xor(v, o);
            if ((tid & 63) == 0) red[wid][gt] = v;
        }
    }
    __syncthreads();
    if (tid == 0) {
        #pragma unroll
        for (int gt = 0; gt < 4; ++gt)
            negE[bid * 4 + gt] = red[0][gt] + red[1][gt] + red[2][gt] + red[3][gt];
    }
}

// 32 blocks x 256 threads: pos rows + ticket finalize.
__global__ __launch_bounds__(256) void posfin(
    const float* __restrict__ P0a, const float* __restrict__ P0b,
    const float* __restrict__ b1, const float* __restrict__ W2,
    const float* __restrict__ b2, const float* __restrict__ negE,
    float* __restrict__ posP, unsigned int* __restrict__ counter,
    float* __restrict__ out)
{
    __shared__ __align__(16) float w2s[HID];
    __shared__ __align__(16) float b1s[HID];
    __shared__ float red[4][1];
    __shared__ int sh_last;
    const int tid = threadIdx.x, bid = blockIdx.x;
    const int wid = tid >> 6, lane = tid & 63;
    const float b2v = b2[0];

    for (int idx = tid; idx < HID; idx += 256) {
        w2s[idx] = W2[idx];
        b1s[idx] = b1[idx];
    }
    __syncthreads();
    const int rl = tid >> 2, qq = tid & 3;
    const int i = bid * 64 + rl;
    const int q0 = qq * 19;
    const int q1 = (qq == 3) ? HID / 4 : q0 + 19;
    const float4* ra = (const float4*)(P0a + (size_t)i * GSTR);
    const float4* rb = (const float4*)(P0b + (size_t)i * GSTR);
    float acc = 0.f;
    for (int k4 = q0; k4 < q1; ++k4) {
        const float4 aa = ra[k4], bb4 = rb[k4];
        const float4 bb = *(const float4*)&b1s[k4 * 4];
        const float4 wv = *(const float4*)&w2s[k4 * 4];
        acc += fmaxf(aa.x + bb4.x + bb.x, 0.f) * wv.x
             + fmaxf(aa.y + bb4.y + bb.y, 0.f) * wv.y
             + fmaxf(aa.z + bb4.z + bb.z, 0.f) * wv.z
             + fmaxf(aa.w + bb4.w + bb.w, 0.f) * wv.w;
    }
    acc += __shfl_xor(acc, 1);
    acc += __shfl_xor(acc, 2);
    float sp = (qq == 0) ? softplus_f(acc + b2v) : 0.f;
    #pragma unroll
    for (int o = 32; o > 0; o >>= 1) sp += __shfl_xor(sp, o);
    if (lane == 0) red[wid][0] = sp;
    __syncthreads();
    if (tid == 0)
        posP[bid] = red[0][0] + red[1][0] + red[2][0] + red[3][0];

    // ---- last-block finalize (device-scope ticket over 32 blocks) ----
    if (tid == 0) {
        __threadfence();
        const unsigned t = atomicAdd(counter, 1u);
        sh_last = (t == NPOS - 1) ? 1 : 0;
    }
    __syncthreads();
    if (sh_last) {
        __threadfence();
        const volatile float* ne = (const volatile float*)negE;
        const volatile float* pp = (const volatile float*)posP;
        float v = 0.f;
        for (int i2 = tid; i2 < 2048; i2 += 256)
            v += __logf(ne[i2]);
        if (tid < NPOS) v -= pp[tid];
        #pragma unroll
        for (int o = 32; o > 0; o >>= 1) v += __shfl_xor(v, o);
        if (lane == 0) red[wid][0] = v;
        __syncthreads();
        if (tid == 0)
            out[0] = (red[0][0] + red[1][0] + red[2][0] + red[3][0]) * (1.f / 2048.f);
    }
}

extern "C" void kernel_launch(void* const* d_in, const int* in_sizes, int n_in,
                              void* d_out, int out_size, void* d_ws, size_t ws_size,
                              hipStream_t stream)
{
    const float* pl = (const float*)d_in[0];
    const float* pg = (const float*)d_in[1];
    const float* nl = (const float*)d_in[2];
    const float* ng = (const float*)d_in[3];
    const float* W1 = (const float*)d_in[4];
    const float* b1 = (const float*)d_in[5];
    const float* W2 = (const float*)d_in[6];
    const float* b2 = (const float*)d_in[7];

    char* ws = (char*)d_ws;
    unsigned short* Aneg = (unsigned short*)(ws);                 // 4 MB
    unsigned short* Apos = (unsigned short*)(ws + (4u << 20));    // 4 MB
    unsigned short* Wt   = (unsigned short*)(ws + (8u << 20));    // 640 KB
    float* LP4  = (float*)(ws + (9u << 20));                      // 80*2048*16B
    float* GPB  = (float*)(ws + (12u << 20));                     // 2.49 MB
    float* P0a  = (float*)(ws + (15u << 20));                     // 2.49 MB
    float* P0b  = (float*)(ws + (18u << 20));                     // 2.49 MB
    float* negE = (float*)(ws + (21u << 20));                     // 2048 f
    float* posP = negE + 2048;                                    // 32 f
    unsigned int* counter = (unsigned int*)(ws + (21u << 20) + 65536);
    float* out  = (float*)d_out;

    hipLaunchKernelGGL(convert, dim3(4096 + 320), dim3(256), 0, stream,
                       pl, pg, nl, ng, W1, Aneg, Apos, Wt, counter);
    hipLaunchKernelGGL(mfma_gemm, dim3(NR / 32, NPAD / 32, 4), dim3(64), 0, stream,
                       Aneg, Apos, Wt, b1, LP4, GPB, P0a, P0b);
    hipLaunchKernelGGL(neg_kernel, dim3(512), dim3(512), 0, stream,
                       LP4, GPB, W2, b2, negE);
    hipLaunchKernelGGL(posfin, dim3(NPOS), dim3(256), 0, stream,
                       P0a, P0b, b1, W2, b2, negE, posP, counter, out);
}

// Round 12
// 62.314 us; speedup vs baseline: 1.1101x; 1.1101x over previous
//
#include <hip/hip_runtime.h>
#include <math.h>

#define NR   2048
#define XD   512
#define HID  300
#define BS   256
#define NPAD 320
#define KTOT 1024
#define GSTR 304          // row stride for GPB/P0a/P0b (float4-aligned)
#define KP   320          // padded k (80 k4-slots; slots 75..79 exact zeros)
#define NNEG 256          // negpos blocks (1 per CU)

typedef __attribute__((ext_vector_type(8))) short bf16x8;
typedef __attribute__((ext_vector_type(4))) float f32x4;

__device__ __forceinline__ float softplus_f(float x) {
    return fmaxf(x, 0.f) + log1pf(__expf(-fabsf(x)));
}
__device__ __forceinline__ unsigned short f2bf(float f) {
    unsigned int u = __float_as_uint(f);
    u += 0x7FFFu + ((u >> 16) & 1u);   // RNE
    return (unsigned short)(u >> 16);
}

// grid.x = 2048 (Aneg rows) + 2048 (Apos rows) + 320 (Wt tiles)
__global__ __launch_bounds__(256) void convert(
    const float* __restrict__ pl, const float* __restrict__ pg,
    const float* __restrict__ nl, const float* __restrict__ ng,
    const float* __restrict__ W1,
    unsigned short* __restrict__ Aneg, unsigned short* __restrict__ Apos,
    unsigned short* __restrict__ Wt, unsigned int* __restrict__ counter)
{
    const int b = blockIdx.x, tid = threadIdx.x;
    if (b == 0 && tid == 0) *counter = 0u;   // reset ticket each call
    if (b < 4096) {
        const int m = (b < 2048) ? b : b - 2048;
        const float* lo = (b < 2048) ? nl : pl;
        const float* hi = (b < 2048) ? ng : pg;
        unsigned short* dst = (b < 2048) ? Aneg : Apos;
        const int kq = tid * 4;
        const float4 v = (kq < XD) ? *(const float4*)(lo + m * XD + kq)
                                   : *(const float4*)(hi + m * XD + kq - XD);
        ushort4 o;
        o.x = f2bf(v.x); o.y = f2bf(v.y); o.z = f2bf(v.z); o.w = f2bf(v.w);
        *(ushort4*)(dst + m * KTOT + kq) = o;
    } else {
        // W1 [1024][300] -> Wt [320][1024] bf16, zero-padded rows 300..319
        __shared__ unsigned short ts[16][72];
        const int t = b - 4096;
        const int nt = t % 20, kt = t / 20;   // 20 n-tiles x 16 k-tiles
        const int n = nt * 16 + (tid & 15);
        const int kl = tid >> 4;
        #pragma unroll
        for (int j = 0; j < 4; ++j) {
            const int k = kt * 64 + kl * 4 + j;
            ts[tid & 15][kl * 4 + j] = f2bf((n < HID) ? W1[k * HID + n] : 0.f);
        }
        __syncthreads();
        const int nw = tid >> 4, kw = (tid & 15) * 4;
        ushort4 o;
        o.x = ts[nw][kw]; o.y = ts[nw][kw + 1]; o.z = ts[nw][kw + 2]; o.w = ts[nw][kw + 3];
        *(ushort4*)(Wt + (nt * 16 + nw) * KTOT + kt * 64 + kw) = o;
    }
}

// One wave per block, 32x32 tile of 16x16x32 MFMAs, all jobs K=512.
// job 0 writes ALL n<320 -> LP4 k4-slots 75..79 are exact zeros.
__global__ __launch_bounds__(64) void mfma_gemm(
    const unsigned short* __restrict__ Aneg, const unsigned short* __restrict__ Apos,
    const unsigned short* __restrict__ Wt, const float* __restrict__ b1,
    float* __restrict__ LP4, float* __restrict__ GPB,
    float* __restrict__ P0a, float* __restrict__ P0b)
{
    const int job = blockIdx.z;
    const int m0 = blockIdx.x * 32, n0 = blockIdx.y * 32;
    const int lane = threadIdx.x;
    const int r = lane & 15, g = lane >> 4;

    const unsigned short* A = (job >= 2) ? Apos : Aneg;
    const int kbeg = (job & 1) ? XD : 0;

    const unsigned short* a0p = A  + (m0 + r) * KTOT + kbeg + 8 * g;
    const unsigned short* a1p = a0p + 16 * KTOT;
    const unsigned short* b0p = Wt + (n0 + r) * KTOT + kbeg + 8 * g;
    const unsigned short* b1p = b0p + 16 * KTOT;

    f32x4 acc00 = {0,0,0,0}, acc01 = {0,0,0,0}, acc10 = {0,0,0,0}, acc11 = {0,0,0,0};

    #pragma unroll
    for (int k = 0; k < XD; k += 32) {
        const bf16x8 a0 = *(const bf16x8*)(a0p + k);
        const bf16x8 a1 = *(const bf16x8*)(a1p + k);
        const bf16x8 w0 = *(const bf16x8*)(b0p + k);
        const bf16x8 w1 = *(const bf16x8*)(b1p + k);
        acc00 = __builtin_amdgcn_mfma_f32_16x16x32_bf16(a0, w0, acc00, 0, 0, 0);
        acc01 = __builtin_amdgcn_mfma_f32_16x16x32_bf16(a0, w1, acc01, 0, 0, 0);
        acc10 = __builtin_amdgcn_mfma_f32_16x16x32_bf16(a1, w0, acc10, 0, 0, 0);
        acc11 = __builtin_amdgcn_mfma_f32_16x16x32_bf16(a1, w1, acc11, 0, 0, 0);
    }

    f32x4 accs[2][2] = {{acc00, acc01}, {acc10, acc11}};
    #pragma unroll
    for (int mi = 0; mi < 2; ++mi) {
        #pragma unroll
        for (int ni = 0; ni < 2; ++ni) {
            const int n = n0 + ni * 16 + r;
            const int mb = m0 + mi * 16 + 4 * g;
            const f32x4 v = accs[mi][ni];
            if (job == 0) {
                float* base = LP4 + ((size_t)(n >> 2) * NR + mb) * 4 + (n & 3);
                base[0] = v[0]; base[4] = v[1]; base[8] = v[2]; base[12] = v[3];
            } else if (n < HID) {
                const float bias = (job == 1) ? b1[n] : 0.f;
                float* out = (job == 1) ? GPB : ((job == 2) ? P0a : P0b);
                #pragma unroll
                for (int j = 0; j < 4; ++j)
                    out[(size_t)(mb + j) * GSTR + n] = v[j] + bias;
            }
        }
    }
}

// 256 blocks x 512 threads, exactly 1 block/CU:
//  neg: unit = (chunk = bid>>5, 8 g-rows = (bid&31)*8). Waves = k-eighths
//       (kh = tid>>6, 10 k4-slots each, compile-time), lane lh = tid&63,
//       L=4 l-streams. LP traffic halved vs g-tile 4 (78 MB total).
//       w*relu(t) = w't + w'|t| (w'=w/2); k4-slots 75..79 contribute 0.
//  pos: wave kh handles row bid*8+kh.
//  Last block (ticket) does logs + final sum.
__global__ __launch_bounds__(512, 2) void negpos(
    const float* __restrict__ LP4, const float* __restrict__ GPB,
    const float* __restrict__ P0a, const float* __restrict__ P0b,
    const float* __restrict__ b1, const float* __restrict__ W2,
    const float* __restrict__ b2,
    float* __restrict__ negE, float* __restrict__ posP,
    unsigned int* __restrict__ counter, float* __restrict__ out)
{
    __shared__ __align__(16) float w2s[KP];
    __shared__ __align__(16) float gbs[8][KP];        // 10 KB
    __shared__ __align__(16) float pacc[8][BS][8];    // 64 KB
    __shared__ float sC[8];
    __shared__ float red[4][8];
    __shared__ float redp[8];
    __shared__ int sh_last;
    const int tid = threadIdx.x, bid = blockIdx.x;
    const int kh = tid >> 6, lh = tid & 63;
    const float b2v = b2[0];

    const int chunk = bid >> 5, g0 = (bid & 31) * 8;
    const float* gp = GPB + (size_t)(chunk * BS + g0) * GSTR;
    for (int idx = tid; idx < KP; idx += 512) {
        const bool v = idx < HID;
        w2s[idx] = v ? 0.5f * W2[idx] : 0.f;
        #pragma unroll
        for (int g = 0; g < 8; ++g)
            gbs[g][idx] = v ? gp[g * GSTR + idx] : 0.f;
    }
    __syncthreads();

    // sC[g] = sum_k w'_k gp[g][k]; wave kh handles g-row kh (padded zeros)
    {
        float c = 0.f;
        #pragma unroll
        for (int h = 0; h < 2; ++h) {
            const int k4 = lh + 64 * h;
            if (k4 < 80) {
                const float4 g4 = *(const float4*)&gbs[kh][k4 * 4];
                const float4 w4 = *(const float4*)&w2s[k4 * 4];
                c += g4.x * w4.x + g4.y * w4.y + g4.z * w4.z + g4.w * w4.w;
            }
        }
        #pragma unroll
        for (int o = 32; o > 0; o >>= 1) c += __shfl_xor(c, o);
        if (lh == 0) sC[kh] = c;
    }

    // main loop: 10 k4-slots per wave, compile-time trip count
    const int k4beg = 10 * kh;
    const float4* lpb = (const float4*)LP4 + (chunk * BS + lh);

    float acc[8][4];      // [gt][j]
    float q[4] = {0.f, 0.f, 0.f, 0.f};
    #pragma unroll
    for (int gt = 0; gt < 8; ++gt)
        #pragma unroll
        for (int j = 0; j < 4; ++j) acc[gt][j] = 0.f;

    #pragma unroll
    for (int i = 0; i < 10; ++i) {
        const int k4 = k4beg + i;
        float4 a[4];
        #pragma unroll
        for (int j = 0; j < 4; ++j)
            a[j] = lpb[(size_t)k4 * NR + 64 * j];
        const float4 w4 = *(const float4*)&w2s[k4 * 4];
        #pragma unroll
        for (int j = 0; j < 4; ++j) {
            q[j] = fmaf(w4.x, a[j].x, q[j]);
            q[j] = fmaf(w4.y, a[j].y, q[j]);
            q[j] = fmaf(w4.z, a[j].z, q[j]);
            q[j] = fmaf(w4.w, a[j].w, q[j]);
        }
        #pragma unroll
        for (int gt = 0; gt < 8; ++gt) {
            const float4 g4 = *(const float4*)&gbs[gt][k4 * 4];
            #pragma unroll
            for (int j = 0; j < 4; ++j) {
                acc[gt][j] = fmaf(fabsf(g4.x + a[j].x), w4.x, acc[gt][j]);
                acc[gt][j] = fmaf(fabsf(g4.y + a[j].y), w4.y, acc[gt][j]);
                acc[gt][j] = fmaf(fabsf(g4.z + a[j].z), w4.z, acc[gt][j]);
                acc[gt][j] = fmaf(fabsf(g4.w + a[j].w), w4.w, acc[gt][j]);
            }
        }
    }

    #pragma unroll
    for (int j = 0; j < 4; ++j) {
        *(float4*)&pacc[kh][lh + 64 * j][0] =
            make_float4(acc[0][j] + q[j], acc[1][j] + q[j],
                        acc[2][j] + q[j], acc[3][j] + q[j]);
        *(float4*)&pacc[kh][lh + 64 * j][4] =
            make_float4(acc[4][j] + q[j], acc[5][j] + q[j],
                        acc[6][j] + q[j], acc[7][j] + q[j]);
    }
    __syncthreads();   // pacc + sC ready

    // combine: thread tid<256 = l; s[gt] = sC[gt] + sum_kh pacc[kh][l][gt]
    if (tid < 256) {
        float s[8];
        #pragma unroll
        for (int gt = 0; gt < 8; ++gt) s[gt] = sC[gt];
        #pragma unroll
        for (int k = 0; k < 8; ++k) {
            const float4 p0 = *(const float4*)&pacc[k][tid][0];
            const float4 p1 = *(const float4*)&pacc[k][tid][4];
            s[0] += p0.x; s[1] += p0.y; s[2] += p0.z; s[3] += p0.w;
            s[4] += p1.x; s[5] += p1.y; s[6] += p1.z; s[7] += p1.w;
        }
        const int wid = tid >> 6;
        #pragma unroll
        for (int gt = 0; gt < 8; ++gt) {
            float v = __expf(softplus_f(s[gt] + b2v));
            #pragma unroll
            for (int o = 32; o > 0; o >>= 1) v += __shfl_xor(v, o);
            if ((tid & 63) == 0) red[wid][gt] = v;
        }
    }
    __syncthreads();
    if (tid == 0) {
        #pragma unroll
        for (int gt = 0; gt < 8; ++gt)
            negE[bid * 8 + gt] = red[0][gt] + red[1][gt] + red[2][gt] + red[3][gt];
    }

    // ---- positive term: wave kh handles row bid*8 + kh ----
    {
        const int row = bid * 8 + kh;
        const float4* ra = (const float4*)(P0a + (size_t)row * GSTR);
        const float4* rb = (const float4*)(P0b + (size_t)row * GSTR);
        float d = 0.f;
        #pragma unroll
        for (int h = 0; h < 2; ++h) {
            const int k4 = lh + 64 * h;
            if (k4 < 75) {
                const float4 aa = ra[k4], bb4 = rb[k4];
                const float4 bb = *(const float4*)(b1 + k4 * 4);
                const float4 wv = *(const float4*)(W2 + k4 * 4);
                d += fmaxf(aa.x + bb4.x + bb.x, 0.f) * wv.x
                   + fmaxf(aa.y + bb4.y + bb.y, 0.f) * wv.y
                   + fmaxf(aa.z + bb4.z + bb.z, 0.f) * wv.z
                   + fmaxf(aa.w + bb4.w + bb.w, 0.f) * wv.w;
            }
        }
        #pragma unroll
        for (int o = 32; o > 0; o >>= 1) d += __shfl_xor(d, o);
        if (lh == 0) redp[kh] = softplus_f(d + b2v);
    }
    __syncthreads();

    // ---- last-block finalize (device-scope ticket over 256 blocks) ----
    if (tid == 0) {
        posP[bid] = redp[0] + redp[1] + redp[2] + redp[3]
                  + redp[4] + redp[5] + redp[6] + redp[7];
        __threadfence();
        const unsigned t = atomicAdd(counter, 1u);
        sh_last = (t == NNEG - 1) ? 1 : 0;
    }
    __syncthreads();
    if (sh_last) {
        __threadfence();
        const volatile float* ne = (const volatile float*)negE;
        const volatile float* pp = (const volatile float*)posP;
        float v = 0.f;
        for (int i = tid; i < 2048; i += 512)
            v += __logf(ne[i]);
        if (tid < NNEG) v -= pp[tid];
        #pragma unroll
        for (int o = 32; o > 0; o >>= 1) v += __shfl_xor(v, o);
        if (lh == 0) redp[kh] = v;
        __syncthreads();
        if (tid == 0)
            out[0] = (redp[0] + redp[1] + redp[2] + redp[3]
                    + redp[4] + redp[5] + redp[6] + redp[7]) * (1.f / 2048.f);
    }
}

extern "C" void kernel_launch(void* const* d_in, const int* in_sizes, int n_in,
                              void* d_out, int out_size, void* d_ws, size_t ws_size,
                              hipStream_t stream)
{
    const float* pl = (const float*)d_in[0];
    const float* pg = (const float*)d_in[1];
    const float* nl = (const float*)d_in[2];
    const float* ng = (const float*)d_in[3];
    const float* W1 = (const float*)d_in[4];
    const float* b1 = (const float*)d_in[5];
    const float* W2 = (const float*)d_in[6];
    const float* b2 = (const float*)d_in[7];

    char* ws = (char*)d_ws;
    unsigned short* Aneg = (unsigned short*)(ws);                 // 4 MB
    unsigned short* Apos = (unsigned short*)(ws + (4u << 20));    // 4 MB
    unsigned short* Wt   = (unsigned short*)(ws + (8u << 20));    // 640 KB
    float* LP4  = (float*)(ws + (9u << 20));                      // 80*2048*16B
    float* GPB  = (float*)(ws + (12u << 20));                     // 2.49 MB
    float* P0a  = (float*)(ws + (15u << 20));                     // 2.49 MB
    float* P0b  = (float*)(ws + (18u << 20));                     // 2.49 MB
    float* negE = (float*)(ws + (21u << 20));                     // 2048 f
    float* posP = negE + 2048;                                    // 256 f
    unsigned int* counter = (unsigned int*)(ws + (21u << 20) + 65536);
    float* out  = (float*)d_out;

    hipLaunchKernelGGL(convert, dim3(4096 + 320), dim3(256), 0, stream,
                       pl, pg, nl, ng, W1, Aneg, Apos, Wt, counter);
    hipLaunchKernelGGL(mfma_gemm, dim3(NR / 32, NPAD / 32, 4), dim3(64), 0, stream,
                       Aneg, Apos, Wt, b1, LP4, GPB, P0a, P0b);
    hipLaunchKernelGGL(negpos, dim3(NNEG), dim3(512), 0, stream,
                       LP4, GPB, P0a, P0b, b1, W2, b2, negE, posP, counter, out);
}